// Round 4
// baseline (363.130 us; speedup 1.0000x reference)
//
#include <hip/hip_runtime.h>

// h_t = f_t*x_t + (1-f_t)*h_{t-1}; SEQ=1024, B*H=32768 channels, fp32,
// layout [t][channel] (channel fastest).
//
// Round-5. Two lessons from rocprof across rounds 1-4:
//  (a) VGPR_Count=32..60 despite declared 128-reg prefetch buffers: the
//      compiler collapsed every prefetch (launch_bounds with default
//      min-waves -> it sank loads to just-before-use). ~4 loads in flight
//      per wave == the observed ~2 TB/s plateau via Little's law.
//      Fix: __launch_bounds__(256, 2) gives a 256-VGPR budget so the
//      4x8-f4 double-buffer (128 VGPRs) can stay live. 16 loads/thread
//      in flight, 8 waves/CU -> ~128 KB/CU outstanding.
//  (b) All previous versions read 128B..1KB segments strided 128KB
//      (few channels x many timesteps) -> DRAM row thrash. Now each block
//      owns a 1024-channel slab: 4 KB contiguous per row visit.
//
// Structure: validated two-pass chunked scan (affine in h: over a chunk
// h_out = A*h_in + B, A = prod(1-f), B = zero-init scan). NCHUNK=32.
// Pass 1: summaries for chunks 0..30  (reads 31/32 of f,x = 248 MB).
// Pass 2: compose h_start per chunk from h0+summaries, scan, store (390 MB).

typedef float f4 __attribute__((ext_vector_type(4)));

#define SEQ 1024
#define NCH 32768
#define S4 (NCH / 4)         // 8192 f4 per timestep row
#define NCHUNK 32
#define CLEN (SEQ / NCHUNK)  // 32 timesteps per chunk
#define CSPLIT 32            // channel slabs
#define CF4 (S4 / CSPLIT)    // 256 f4 per slab row = 4 KB contiguous
#define TPB 256              // one f4 per thread per row
#define UNR 8                // prefetch depth (rows) per buffer

// Pass 1: per-chunk affine summaries. grid (CSPLIT, NCHUNK-1) = 992 blocks.
__global__ __launch_bounds__(TPB, 2) void fm_sum(const float* __restrict__ f,
                                                 const float* __restrict__ x,
                                                 float* __restrict__ Aw,
                                                 float* __restrict__ Bw) {
    const int s = blockIdx.x;                    // channel slab
    const int c = blockIdx.y;                    // time chunk 0..30
    const int ch4 = s * CF4 + threadIdx.x;       // global f4 column
    const size_t base = (size_t)c * CLEN * S4 + ch4;
    const f4* fp = (const f4*)f + base;
    const f4* xp = (const f4*)x + base;

    f4 A = {1.f, 1.f, 1.f, 1.f};
    f4 Bv = {0.f, 0.f, 0.f, 0.f};
    f4 fA[UNR], xA[UNR], fB[UNR], xB[UNR];

#pragma unroll
    for (int j = 0; j < UNR; ++j) {
        fA[j] = fp[(size_t)j * S4];
        xA[j] = xp[(size_t)j * S4];
    }

#pragma unroll 1
    for (int t0 = 0; t0 < CLEN; t0 += 2 * UNR) {  // 2 iterations
#pragma unroll
        for (int j = 0; j < UNR; ++j) {
            fB[j] = fp[(size_t)(t0 + UNR + j) * S4];
            xB[j] = xp[(size_t)(t0 + UNR + j) * S4];
        }
#pragma unroll
        for (int j = 0; j < UNR; ++j) {
            Bv = fA[j] * (xA[j] - Bv) + Bv;   // B' = f*x + (1-f)*B
            A  = A - fA[j] * A;               // A' = (1-f)*A
        }
        if (t0 + 2 * UNR < CLEN) {
#pragma unroll
            for (int j = 0; j < UNR; ++j) {
                fA[j] = fp[(size_t)(t0 + 2 * UNR + j) * S4];
                xA[j] = xp[(size_t)(t0 + 2 * UNR + j) * S4];
            }
        }
#pragma unroll
        for (int j = 0; j < UNR; ++j) {
            Bv = fB[j] * (xB[j] - Bv) + Bv;
            A  = A - fB[j] * A;
        }
    }

    ((f4*)Aw)[(size_t)c * S4 + ch4] = A;   // cached: pass 2 re-reads these
    ((f4*)Bw)[(size_t)c * S4 + ch4] = Bv;
}

// Pass 2: compose h_start, scan CLEN steps, store. grid (CSPLIT, NCHUNK).
__global__ __launch_bounds__(TPB, 2) void fm_scan(const float* __restrict__ f,
                                                  const float* __restrict__ x,
                                                  const float* __restrict__ h0,
                                                  const float* __restrict__ Aw,
                                                  const float* __restrict__ Bw,
                                                  float* __restrict__ out) {
    const int s = blockIdx.x;
    const int c = blockIdx.y;                    // time chunk 0..31
    const int ch4 = s * CF4 + threadIdx.x;
    const size_t base = (size_t)c * CLEN * S4 + ch4;
    const f4* fp = (const f4*)f + base;
    const f4* xp = (const f4*)x + base;
    f4* op = (f4*)out + base;

    // h_start = h0 advanced through chunks 0..c-1. Batch summary loads 8
    // pairs at a time so the dependent FMA chain doesn't serialize on L2
    // latency per element.
    f4 h = ((const f4*)h0)[ch4];
#pragma unroll 1
    for (int g = 0; g < c; g += 8) {
        f4 av[8], bv[8];
        const int n = (c - g < 8) ? (c - g) : 8;   // block-uniform
#pragma unroll
        for (int k = 0; k < 8; ++k) {
            if (k < n) {
                av[k] = ((const f4*)Aw)[(size_t)(g + k) * S4 + ch4];
                bv[k] = ((const f4*)Bw)[(size_t)(g + k) * S4 + ch4];
            }
        }
#pragma unroll
        for (int k = 0; k < 8; ++k) {
            if (k < n) h = av[k] * h + bv[k];
        }
    }

    f4 fA[UNR], xA[UNR], fB[UNR], xB[UNR];
#pragma unroll
    for (int j = 0; j < UNR; ++j) {
        fA[j] = fp[(size_t)j * S4];
        xA[j] = xp[(size_t)j * S4];
    }

#pragma unroll 1
    for (int t0 = 0; t0 < CLEN; t0 += 2 * UNR) {  // 2 iterations
#pragma unroll
        for (int j = 0; j < UNR; ++j) {
            fB[j] = fp[(size_t)(t0 + UNR + j) * S4];
            xB[j] = xp[(size_t)(t0 + UNR + j) * S4];
        }
#pragma unroll
        for (int j = 0; j < UNR; ++j) {
            h = fA[j] * (xA[j] - h) + h;           // h = f*x + (1-f)*h
            __builtin_nontemporal_store(h, op + (size_t)(t0 + j) * S4);
        }
        if (t0 + 2 * UNR < CLEN) {
#pragma unroll
            for (int j = 0; j < UNR; ++j) {
                fA[j] = fp[(size_t)(t0 + 2 * UNR + j) * S4];
                xA[j] = xp[(size_t)(t0 + 2 * UNR + j) * S4];
            }
        }
#pragma unroll
        for (int j = 0; j < UNR; ++j) {
            h = fB[j] * (xB[j] - h) + h;
            __builtin_nontemporal_store(h, op + (size_t)(t0 + UNR + j) * S4);
        }
    }
}

extern "C" void kernel_launch(void* const* d_in, const int* in_sizes, int n_in,
                              void* d_out, int out_size, void* d_ws, size_t ws_size,
                              hipStream_t stream) {
    const float* f  = (const float*)d_in[0];
    const float* x  = (const float*)d_in[1];
    const float* h0 = (const float*)d_in[2];
    float* out = (float*)d_out;

    // Workspace: (NCHUNK-1)*NCH floats for A and for B -> 8.1 MB total.
    float* Aw = (float*)d_ws;
    float* Bw = Aw + (size_t)(NCHUNK - 1) * NCH;

    fm_sum<<<dim3(CSPLIT, NCHUNK - 1), dim3(TPB), 0, stream>>>(f, x, Aw, Bw);
    fm_scan<<<dim3(CSPLIT, NCHUNK), dim3(TPB), 0, stream>>>(f, x, h0, Aw, Bw, out);
}